// Round 9
// baseline (191.561 us; speedup 1.0000x reference)
//
#include <hip/hip_runtime.h>

#define NLAYER 7
#define IMGB 16384          // bytes per weight-layer image: A[n][k] fp8, 16B-chunk XOR-swizzled (key n&7)
#define WSCALE 16.0f        // weights stored x16 (e4m3 subnormal protection)

typedef __attribute__((ext_vector_type(2))) float float2v;
typedef __attribute__((ext_vector_type(4))) float float4v;
typedef __attribute__((ext_vector_type(4))) unsigned int uint4v;
typedef __attribute__((ext_vector_type(4))) int int4v;
typedef __attribute__((ext_vector_type(8))) int int8v;
typedef unsigned long long u64;

__device__ __forceinline__ float2v pk_fma(float2v a, float2v b, float2v c){
  return __builtin_elementwise_fma(a, b, c);
}
__device__ __forceinline__ float2v lo2(float4v v){ return (float2v){v[0], v[1]}; }
__device__ __forceinline__ float2v hi2(float4v v){ return (float2v){v[2], v[3]}; }

// pack 4 f32 -> 4 fp8 e4m3 bytes (ascending)
__device__ __forceinline__ unsigned pk4fp8(float v0, float v1, float v2, float v3){
  int w = __builtin_amdgcn_cvt_pk_fp8_f32(v0, v1, 0, false);
  w = __builtin_amdgcn_cvt_pk_fp8_f32(v2, v3, w, true);
  return (unsigned)w;
}
template<bool HI>
__device__ __forceinline__ float2v up2(unsigned w){
  return __builtin_amdgcn_cvt_pk_f32_fp8((int)w, HI);
}
// MX-scaled MFMA, K=128, FMT=fp8 e4m3 both operands, scales = 1.0 (E8M0 0x7F)
__device__ __forceinline__ float4v mfma128(int8v a, int8v b){
  return __builtin_amdgcn_mfma_scale_f32_16x16x128_f8f6f4(
      a, b, (float4v){0.f,0.f,0.f,0.f}, 0, 0, 0, 0x7F7F7F7F, 0, 0x7F7F7F7F);
}
// P16 = 16*Phi(z) (cubic Taylor), gp16 = 16*gelu'(z)
__device__ __forceinline__ void act2(float2v z, float2v& P16, float2v& gp16){
  const float2v c1v  = {6.3830764862829235f, 6.3830764862829235f};
  const float2v c3v  = {-1.0638460810704874f, -1.0638460810704874f};
  const float2v c33v = {-3.1915382432114624f, -3.1915382432114624f};
  const float2v v8   = {8.f, 8.f};
  float2v z2 = z * z;
  float2v u  = pk_fma(z2, c3v, c1v);
  P16 = pk_fma(z, u, v8);
  float2v Pd = pk_fma(z2, c33v, c1v);
  gp16 = pk_fma(z, Pd, P16);
}

__device__ __forceinline__ void gl2lds16(const unsigned char* g, unsigned char* l){
  __builtin_amdgcn_global_load_lds((const __attribute__((address_space(1))) unsigned int*)g,
                                   (__attribute__((address_space(3))) unsigned int*)l,
                                   16, 0, 0);
}

// operand gather: 32 contiguous k-bytes from a 16B-swizzled row (key row&7).
// lp/hp pre-compensate the key-bit0 half-swap so k-order is preserved; all
// per-layer/tile displacements fold into ds_read immediate offsets.
__device__ __forceinline__ int8v ld_op16(const unsigned char* lp, const unsigned char* hp){
  int4v lo = *(const int4v*)(lp);
  int4v hi = *(const int4v*)(hp);
  return __builtin_shufflevector(lo, hi, 0, 1, 2, 3, 4, 5, 6, 7);
}

// ---- prep: Wh fp32 [side][term][L][k][n] -> fp8 image [net][L][n][16B chunk c4 ^ (n&7)], W*16 ----
__global__ __launch_bounds__(256)
void prep_weights(const float* __restrict__ lWh,
                  const float* __restrict__ rWh,
                  unsigned char* __restrict__ wbf)
{
  __shared__ __align__(16) unsigned char T[IMGB];
  const int b = blockIdx.x;               // net*7 + L
  const int net = b / NLAYER, L = b % NLAYER;
  const int side = net >> 1, term = net & 1;
  const float* src = (side ? rWh : lWh) + (size_t)((term*NLAYER + L)*128)*128;
  const int t = threadIdx.x;
  {
    const int k = t >> 1, n0 = (t & 1)*64;
    const float* row = src + k*128 + n0;
    #pragma unroll
    for (int c4 = 0; c4 < 4; ++c4){
      float4v f0 = *(const float4v*)(row + c4*16);
      float4v f1 = *(const float4v*)(row + c4*16 + 4);
      float4v f2 = *(const float4v*)(row + c4*16 + 8);
      float4v f3 = *(const float4v*)(row + c4*16 + 12);
      uint4v wv = { pk4fp8(f0[0]*WSCALE, f0[1]*WSCALE, f0[2]*WSCALE, f0[3]*WSCALE),
                    pk4fp8(f1[0]*WSCALE, f1[1]*WSCALE, f1[2]*WSCALE, f1[3]*WSCALE),
                    pk4fp8(f2[0]*WSCALE, f2[1]*WSCALE, f2[2]*WSCALE, f2[3]*WSCALE),
                    pk4fp8(f3[0]*WSCALE, f3[1]*WSCALE, f3[2]*WSCALE, f3[3]*WSCALE) };
      *(uint4v*)&T[k*128 + n0 + c4*16] = wv;
    }
  }
  __syncthreads();
  {
    const int n = t >> 1, c0 = (t & 1)*8;
    const int sw7 = n & 7;
    unsigned char* dst = wbf + ((size_t)b << 14) + n*128;
    #pragma unroll
    for (int c = 0; c < 8; ++c){
      const int c64 = c0 + c;                 // u64 chunk 0..15, k in [c64*8, c64*8+8)
      const int kc = c64*8;
      u64 v = 0;
      #pragma unroll
      for (int j = 0; j < 8; ++j)
        v |= (u64)T[(kc + j)*128 + n] << (8*j);
      *(u64*)(dst + (((c64 >> 1) ^ sw7)*16) + (c64 & 1)*8) = v;
    }
  }
}

// R6 structure (512 thr / 8 waves / 64 elems / ping-pong sH / ONE barrier per layer)
// with the hidden-layer body software-interleaved: {MFMA t0,t1; EPI0; MFMA t2;
// EPI1; MFMA t3; EPI2; EPI3}, pinned by sched_group_barrier, so each wave
// alternates MFMA/VALU demand at fine grain and the 4 waves/SIMD keep BOTH
// pipes fed (R6 counters: MfmaUtil 19% + VALUBusy 48% = 67% combined issue,
// phase-convoy limited).
// LDS = 2*16K (sW dbuf) + 2*16K (sH ping-pong) = 64KB -> exactly 2 blocks/CU.
__global__ __launch_bounds__(512)
__attribute__((amdgpu_waves_per_eu(4, 4)))
void sympl_main(const float* __restrict__ X,
                const float* __restrict__ lW0, const float* __restrict__ lb0,
                const float* __restrict__ lbh, const float* __restrict__ lWo,
                const float* __restrict__ rW0, const float* __restrict__ rb0,
                const float* __restrict__ rbh, const float* __restrict__ rWo,
                const int* __restrict__ lidx, const int* __restrict__ ridx,
                const unsigned char* __restrict__ wbf,
                float* __restrict__ out)
{
  __shared__ __align__(16) unsigned char sWb[2*IMGB];   // weight double-buffer
  __shared__ __align__(16) unsigned char sH[2*16384];
  // parity P (0/16384): H row e at P + e*128, D at P + 8192 + e*128
  // element row e, 16B chunk c4: byte (c4 ^ (e&7))*16 within the row

  const int tid  = threadIdx.x;
  const int lane = tid & 63;
  const int w    = tid >> 6;        // wave 0..7
  const int m0   = lane & 15;
  const int q    = lane >> 4;
  const int g2   = w & 3;           // element group (16 elems each)
  const int ih   = w >> 2;          // n_out half (tiles ih*4 .. ih*4+3)
  const int col  = blockIdx.y;
  const int e0   = blockIdx.x * 64;
  const int r    = tid >> 3;        // element 0..63 (8 threads each)
  const int sg   = tid & 7;
  const int r7   = r & 7;
  const int m06  = m0 & 6;
  const int m07  = m0 & 7;

  const int lt = (lidx[0] == col) ? 0 : 1;
  const int rt = (ridx[0] == col) ? 0 : 1;

  float qv = X[(e0 + r)*4 + col];
  float pv = X[(e0 + r)*4 + 2 + col];

  const float dt = 0.1f;
  const float C0 = 0.6756035959798289f, C1 = -0.17560359597982883f;
  const float D0 = 1.3512071919596578f, D1 = -1.7024143839193153f;
  // fold 1/(16*4^7) = 1/262144 (final S_d scale) into the step coefficients
  const float is = 1.0f / 262144.0f;
  const float coefs[7] = { C0*dt*is, -D0*dt*is, C1*dt*is, -D1*dt*is,
                           C1*dt*is, -D0*dt*is, C0*dt*is };

  const float2v inv256v = {1.f/256.f, 1.f/256.f};
  const float2v inv64v  = {1.f/64.f, 1.f/64.f};

  // hoisted, loop-invariant LDS addresses; parity (0/16384), stream (+8192) and
  // tile (i*2048) displacements fold into ds immediate offsets after full unroll.
  const int lo16 = (m0 & 1) * 16;
  const int opo  = ((2*q) ^ m06) * 16;
  const unsigned char* pB0lo = sH + (g2*16 + m0)*128 + opo + lo16;
  const unsigned char* pB0hi = sH + (g2*16 + m0)*128 + opo + 16 - lo16;
  const unsigned char* pA0lo = sWb + (ih*64 + m0)*128 + opo + lo16;
  const unsigned char* pA0hi = sWb + (ih*64 + m0)*128 + opo + 16 - lo16;
  unsigned char* pHe = sH + (g2*16 + m0)*128;                 // epilogue write base
  unsigned char* pL0 = sH + r*128 + ((sg ^ r7)*16);           // layer-0 write base (parity 0)
  const unsigned char* pRd = sH + 16384 + 8192 + r*128 + ((sg ^ r7)*16);  // reduce (parity 1, S_d)
  const int q4 = q * 4;
  unsigned char* pE0 = pHe + ((ih*4 + 0) ^ m07)*16 + q4;      // epilogue chunk pointers
  unsigned char* pE1 = pHe + ((ih*4 + 1) ^ m07)*16 + q4;
  unsigned char* pE2 = pHe + ((ih*4 + 2) ^ m07)*16 + q4;
  unsigned char* pE3 = pHe + ((ih*4 + 3) ^ m07)*16 + q4;

  // prologue: stage sW buffer 0 for ev=0 (right net, term rt, L=0)
  {
    const unsigned char* src = wbf + (size_t)(2 + rt)*NLAYER*IMGB;
    #pragma unroll
    for (int it = 0; it < 2; ++it){
      int o = (it*512 + tid) * 16;
      gl2lds16(src + o, sWb + o);
    }
  }
  __syncthreads();

  for (int ev = 0; ev < 7; ++ev){
    const bool isT = !(ev & 1);
    const int  evp = ev & 1;          // sW parity generator: par(L) = evp ^ (L&1)
    const int  term = isT ? rt : lt;
    const float* W0p = (isT ? rW0 : lW0) + term*128;
    const float* b0p = (isT ? rb0 : lb0) + term*128;
    const float* bhp = (isT ? rbh : lbh) + term*NLAYER*128;
    const float* Wop = (isT ? rWo : lWo) + term*128;
    const unsigned char* wimg = wbf + (size_t)(((isT ? 2 : 0) + term)*NLAYER)*IMGB;
    const int tnx = (ev & 1) ? rt : lt;
    const unsigned char* wimg_nx = wbf + (size_t)((((ev & 1) ? 2 : 0) + tnx)*NLAYER)*IMGB;

    // ---- layer 0: S_h = 16*gelu(z), S_d = 16*gelu'(z)*w, z = x*w+b  (parity 0) ----
    {
      const float x = isT ? pv : qv;
      const float2v xv = {x, x};
      unsigned hw[4], dw[4];
      #pragma unroll
      for (int c = 0; c < 2; ++c){
        int n0 = sg*16 + c*8;
        float4v wa = *(const float4v*)(W0p + n0);
        float4v wb = *(const float4v*)(W0p + n0 + 4);
        float4v ba = *(const float4v*)(b0p + n0);
        float4v bb2 = *(const float4v*)(b0p + n0 + 4);
        float2v zp[4] = { pk_fma(xv, lo2(wa), lo2(ba)), pk_fma(xv, hi2(wa), hi2(ba)),
                          pk_fma(xv, lo2(wb), lo2(bb2)), pk_fma(xv, hi2(wb), hi2(bb2)) };
        float2v wp[4] = { lo2(wa), hi2(wa), lo2(wb), hi2(wb) };
        float Sh[8], Sd[8];
        #pragma unroll
        for (int pp = 0; pp < 4; ++pp){
          float2v P16, gp16; act2(zp[pp], P16, gp16);
          float2v h = zp[pp] * P16;
          float2v d = gp16 * wp[pp];
          Sh[pp*2] = h[0]; Sh[pp*2+1] = h[1];
          Sd[pp*2] = d[0]; Sd[pp*2+1] = d[1];
        }
        hw[c*2]   = pk4fp8(Sh[0],Sh[1],Sh[2],Sh[3]);
        hw[c*2+1] = pk4fp8(Sh[4],Sh[5],Sh[6],Sh[7]);
        dw[c*2]   = pk4fp8(Sd[0],Sd[1],Sd[2],Sd[3]);
        dw[c*2+1] = pk4fp8(Sd[4],Sd[5],Sd[6],Sd[7]);
      }
      *(uint4v*)(pL0)        = (uint4v){hw[0], hw[1], hw[2], hw[3]};
      *(uint4v*)(pL0 + 8192) = (uint4v){dw[0], dw[1], dw[2], dw[3]};
    }
    asm volatile("s_waitcnt lgkmcnt(0)" ::: "memory");
    __builtin_amdgcn_s_barrier();
    asm volatile("" ::: "memory");

    // ---- hidden layers: ping-pong sH, ONE barrier per layer ----
    #pragma unroll
    for (int L = 0; L < NLAYER; ++L){
      const int rdo = (L & 1) * 16384;      // sH read parity (compile-time)
      const int wro = rdo ^ 16384;          // sH write parity
      const int par = (L & 1) ? (evp ^ 1) : evp;   // sW read buffer (uniform)
      const int bufo = par ? IMGB : 0;

      // bias loads FIRST (oldest vmem): epilogue's bias wait leaves staging in flight
      const float* bias = bhp + L*128 + ih*64 + q4;
      float4v bv0 = *(const float4v*)(bias);
      float4v bv1 = *(const float4v*)(bias + 16);
      float4v bv2 = *(const float4v*)(bias + 32);
      float4v bv3 = *(const float4v*)(bias + 48);

      // stage NEXT weight tile into the other sW buffer; drains at end-of-layer barrier
      if (!(ev == 6 && L == 6)){
        const unsigned char* nsrc = (L < 6) ? (wimg + (size_t)(L+1)*IMGB) : wimg_nx;
        unsigned char* dW = sWb + (bufo ^ IMGB);
        #pragma unroll
        for (int it = 0; it < 2; ++it){
          int o = (it*512 + tid) * 16;
          gl2lds16(nsrc + o, dW + o);
        }
      }

      const unsigned char* pAcLo = pA0lo + bufo;
      const unsigned char* pAcHi = pA0hi + bufo;

      // 12 ds_read_b128: B fragments + all 4 A tiles
      int8v b0 = ld_op16(pB0lo + rdo, pB0hi + rdo);
      int8v b1 = ld_op16(pB0lo + rdo + 8192, pB0hi + rdo + 8192);
      int8v a0 = ld_op16(pAcLo,          pAcHi);
      int8v a1 = ld_op16(pAcLo + 2048,   pAcHi + 2048);
      int8v a2 = ld_op16(pAcLo + 4096,   pAcHi + 4096);
      int8v a3 = ld_op16(pAcLo + 6144,   pAcHi + 6144);

      // epilogue for one tile: z = accH/256 + b; S_h' = z*P16; S_d' = gp16*(accD/64)
      #define EPI(cH, cD, bvv, pe) { \
        float2v za = pk_fma(lo2(cH), inv256v, lo2(bvv)); \
        float2v zb = pk_fma(hi2(cH), inv256v, hi2(bvv)); \
        float2v ta = lo2(cD) * inv64v; \
        float2v tb = hi2(cD) * inv64v; \
        float2v Pa, ga, Pb, gb; \
        act2(za, Pa, ga); \
        act2(zb, Pb, gb); \
        float2v ha = za * Pa, hb = zb * Pb; \
        float2v da = ga * ta, db = gb * tb; \
        *(unsigned*)(pe + wro)        = pk4fp8(ha[0], ha[1], hb[0], hb[1]); \
        *(unsigned*)(pe + wro + 8192) = pk4fp8(da[0], da[1], db[0], db[1]); \
      }

      // interleaved MFMA / EPI: wave alternates pipe demand at fine grain
      float4v c00 = mfma128(a0, b0);
      float4v c01 = mfma128(a0, b1);
      float4v c10 = mfma128(a1, b0);
      float4v c11 = mfma128(a1, b1);
      EPI(c00, c01, bv0, pE0)
      float4v c20 = mfma128(a2, b0);
      float4v c21 = mfma128(a2, b1);
      EPI(c10, c11, bv1, pE1)
      float4v c30 = mfma128(a3, b0);
      float4v c31 = mfma128(a3, b1);
      EPI(c20, c21, bv2, pE2)
      EPI(c30, c31, bv3, pE3)
      #undef EPI

      // pin the interleave (masks per LLVM SchedGroupMask: VALU=0x2 MFMA=0x8
      // VMEM_READ=0x20 DS_READ=0x100 DS_WRITE=0x200). Groups fill greedily in
      // order; count mismatches degrade gracefully.
      __builtin_amdgcn_sched_group_barrier(0x020, 6, 0);   // bias + staging issue first
      __builtin_amdgcn_sched_group_barrier(0x100, 12, 0);  // all ds_read_b128
      __builtin_amdgcn_sched_group_barrier(0x008, 4, 0);   // mfma t0,t1
      __builtin_amdgcn_sched_group_barrier(0x002, 24, 0);  // EPI0 valu
      __builtin_amdgcn_sched_group_barrier(0x200, 2, 0);   // EPI0 writes
      __builtin_amdgcn_sched_group_barrier(0x008, 2, 0);   // mfma t2
      __builtin_amdgcn_sched_group_barrier(0x002, 24, 0);  // EPI1
      __builtin_amdgcn_sched_group_barrier(0x200, 2, 0);
      __builtin_amdgcn_sched_group_barrier(0x008, 2, 0);   // mfma t3
      __builtin_amdgcn_sched_group_barrier(0x002, 48, 0);  // EPI2+3
      __builtin_amdgcn_sched_group_barrier(0x200, 4, 0);

      // ONE barrier per layer: sH RAW/WAR + sW staging drain.
      asm volatile("s_waitcnt vmcnt(0) lgkmcnt(0)" ::: "memory");
      __builtin_amdgcn_s_barrier();
      asm volatile("" ::: "memory");
    }

    // ---- reduce: s_raw = S_d7 . Wo (= 262144*s); parity-1 D region. No trailing
    // barrier: next eval's conflicting writers sit behind the post-layer0 barrier. ----
    {
      uint4v dvv = *(const uint4v*)(pRd);
      float2v sv = {0.f, 0.f};
      float4v woa = *(const float4v*)(Wop + sg*16);
      float4v wob = *(const float4v*)(Wop + sg*16 + 4);
      float4v woc = *(const float4v*)(Wop + sg*16 + 8);
      float4v wod = *(const float4v*)(Wop + sg*16 + 12);
      sv = pk_fma(up2<false>(dvv[0]), lo2(woa), sv);
      sv = pk_fma(up2<true>(dvv[0]),  hi2(woa), sv);
      sv = pk_fma(up2<false>(dvv[1]), lo2(wob), sv);
      sv = pk_fma(up2<true>(dvv[1]),  hi2(wob), sv);
      sv = pk_fma(up2<false>(dvv[2]), lo2(woc), sv);
      sv = pk_fma(up2<true>(dvv[2]),  hi2(woc), sv);
      sv = pk_fma(up2<false>(dvv[3]), lo2(wod), sv);
      sv = pk_fma(up2<true>(dvv[3]),  hi2(wod), sv);
      float s = sv[0] + sv[1];
      s += __shfl_xor(s, 1);
      s += __shfl_xor(s, 2);
      s += __shfl_xor(s, 4);
      if (isT) qv += coefs[ev] * s;
      else     pv += coefs[ev] * s;
    }
  }

  if (sg == 0){
    out[(e0 + r)*4 + col]     = qv;
    out[(e0 + r)*4 + 2 + col] = pv;
  }
}

extern "C" void kernel_launch(void* const* d_in, const int* in_sizes, int n_in,
                              void* d_out, int out_size, void* d_ws, size_t ws_size,
                              hipStream_t stream)
{
  const float* X   = (const float*)d_in[0];
  const float* lW0 = (const float*)d_in[1];
  const float* lb0 = (const float*)d_in[2];
  const float* lWh = (const float*)d_in[3];
  const float* lbh = (const float*)d_in[4];
  const float* lWo = (const float*)d_in[5];
  const float* rW0 = (const float*)d_in[7];
  const float* rb0 = (const float*)d_in[8];
  const float* rWh = (const float*)d_in[9];
  const float* rbh = (const float*)d_in[10];
  const float* rWo = (const float*)d_in[11];
  const int*   li  = (const int*)d_in[13];
  const int*   ri  = (const int*)d_in[14];
  unsigned char* wbf = (unsigned char*)d_ws;   // 4*7*16384 B = 458752 B
  float* out = (float*)d_out;
  const int B = in_sizes[0] / 4;

  hipLaunchKernelGGL(prep_weights, dim3(4*NLAYER), dim3(256), 0, stream,
                     lWh, rWh, wbf);
  hipLaunchKernelGGL(sympl_main, dim3(B/64, 2), dim3(512), 0, stream,
                     X, lW0, lb0, lbh, lWo, rW0, rb0, rbh, rWo, li, ri, wbf, out);
}

// Round 12
// 181.297 us; speedup vs baseline: 1.0566x; 1.0566x over previous
//
#include <hip/hip_runtime.h>

#define NLAYER 7
#define IMGB 16384          // bytes per weight-layer image: A[n][k] fp8, 16B-chunk XOR-swizzled (key n&7)
#define WSCALE 16.0f        // weights stored x16 (e4m3 subnormal protection)

typedef __attribute__((ext_vector_type(2))) float float2v;
typedef __attribute__((ext_vector_type(4))) float float4v;
typedef __attribute__((ext_vector_type(4))) unsigned int uint4v;
typedef __attribute__((ext_vector_type(4))) int int4v;
typedef __attribute__((ext_vector_type(8))) int int8v;
typedef unsigned long long u64;

__device__ __forceinline__ float2v pk_fma(float2v a, float2v b, float2v c){
  return __builtin_elementwise_fma(a, b, c);
}
__device__ __forceinline__ float2v lo2(float4v v){ return (float2v){v[0], v[1]}; }
__device__ __forceinline__ float2v hi2(float4v v){ return (float2v){v[2], v[3]}; }

// pack 4 f32 -> 4 fp8 e4m3 bytes (ascending)
__device__ __forceinline__ unsigned pk4fp8(float v0, float v1, float v2, float v3){
  int w = __builtin_amdgcn_cvt_pk_fp8_f32(v0, v1, 0, false);
  w = __builtin_amdgcn_cvt_pk_fp8_f32(v2, v3, w, true);
  return (unsigned)w;
}
template<bool HI>
__device__ __forceinline__ float2v up2(unsigned w){
  return __builtin_amdgcn_cvt_pk_f32_fp8((int)w, HI);
}
// MX-scaled MFMA, K=128, FMT=fp8 e4m3 both operands. `sc` is the E8M0 scale
// for the first scale slot (4 packed bytes, one per 32-elem K-block): 0x7F=2^0.
// Scaling either operand scales the product, so the A/B slot binding is
// irrelevant; powers of two are exact -> folding /256 (0x77) and /64 (0x79)
// here is bit-identical to doing the divide in the epilogue.
__device__ __forceinline__ float4v mfma128s(int8v a, int8v b, unsigned sc){
  return __builtin_amdgcn_mfma_scale_f32_16x16x128_f8f6f4(
      a, b, (float4v){0.f,0.f,0.f,0.f}, 0, 0, 0, (int)sc, 0, 0x7F7F7F7F);
}
// P16 = 16*Phi(z) (cubic Taylor), gp16 = 16*gelu'(z)
__device__ __forceinline__ void act2(float2v z, float2v& P16, float2v& gp16){
  const float2v c1v  = {6.3830764862829235f, 6.3830764862829235f};
  const float2v c3v  = {-1.0638460810704874f, -1.0638460810704874f};
  const float2v c33v = {-3.1915382432114624f, -3.1915382432114624f};
  const float2v v8   = {8.f, 8.f};
  float2v z2 = z * z;
  float2v u  = pk_fma(z2, c3v, c1v);
  P16 = pk_fma(z, u, v8);
  float2v Pd = pk_fma(z2, c33v, c1v);
  gp16 = pk_fma(z, Pd, P16);
}

__device__ __forceinline__ void gl2lds16(const unsigned char* g, unsigned char* l){
  __builtin_amdgcn_global_load_lds((const __attribute__((address_space(1))) unsigned int*)g,
                                   (__attribute__((address_space(3))) unsigned int*)l,
                                   16, 0, 0);
}

// operand gather: 32 contiguous k-bytes from a 16B-swizzled row (key row&7).
// lp/hp pre-compensate the key-bit0 half-swap so k-order is preserved; all
// per-layer/tile displacements fold into ds_read immediate offsets.
__device__ __forceinline__ int8v ld_op16(const unsigned char* lp, const unsigned char* hp){
  int4v lo = *(const int4v*)(lp);
  int4v hi = *(const int4v*)(hp);
  return __builtin_shufflevector(lo, hi, 0, 1, 2, 3, 4, 5, 6, 7);
}

// ---- prep: Wh fp32 [side][term][L][k][n] -> fp8 image [net][L][n][16B chunk c4 ^ (n&7)], W*16 ----
__global__ __launch_bounds__(256)
void prep_weights(const float* __restrict__ lWh,
                  const float* __restrict__ rWh,
                  unsigned char* __restrict__ wbf)
{
  __shared__ __align__(16) unsigned char T[IMGB];
  const int b = blockIdx.x;               // net*7 + L
  const int net = b / NLAYER, L = b % NLAYER;
  const int side = net >> 1, term = net & 1;
  const float* src = (side ? rWh : lWh) + (size_t)((term*NLAYER + L)*128)*128;
  const int t = threadIdx.x;
  {
    const int k = t >> 1, n0 = (t & 1)*64;
    const float* row = src + k*128 + n0;
    #pragma unroll
    for (int c4 = 0; c4 < 4; ++c4){
      float4v f0 = *(const float4v*)(row + c4*16);
      float4v f1 = *(const float4v*)(row + c4*16 + 4);
      float4v f2 = *(const float4v*)(row + c4*16 + 8);
      float4v f3 = *(const float4v*)(row + c4*16 + 12);
      uint4v wv = { pk4fp8(f0[0]*WSCALE, f0[1]*WSCALE, f0[2]*WSCALE, f0[3]*WSCALE),
                    pk4fp8(f1[0]*WSCALE, f1[1]*WSCALE, f1[2]*WSCALE, f1[3]*WSCALE),
                    pk4fp8(f2[0]*WSCALE, f2[1]*WSCALE, f2[2]*WSCALE, f2[3]*WSCALE),
                    pk4fp8(f3[0]*WSCALE, f3[1]*WSCALE, f3[2]*WSCALE, f3[3]*WSCALE) };
      *(uint4v*)&T[k*128 + n0 + c4*16] = wv;
    }
  }
  __syncthreads();
  {
    const int n = t >> 1, c0 = (t & 1)*8;
    const int sw7 = n & 7;
    unsigned char* dst = wbf + ((size_t)b << 14) + n*128;
    #pragma unroll
    for (int c = 0; c < 8; ++c){
      const int c64 = c0 + c;                 // u64 chunk 0..15, k in [c64*8, c64*8+8)
      const int kc = c64*8;
      u64 v = 0;
      #pragma unroll
      for (int j = 0; j < 8; ++j)
        v |= (u64)T[(kc + j)*128 + n] << (8*j);
      *(u64*)(dst + (((c64 >> 1) ^ sw7)*16) + (c64 & 1)*8) = v;
    }
  }
}

// R6 champion structure: 512 thr / 8 waves / 64 elems; sH ping-pong (2x16KB) ->
// ONE barrier per layer; sW double-buffered (flat array) with full-layer
// staging overlap. LDS = 2*16K + 2*16K = 64KB -> exactly 2 blocks/CU.
// Deltas vs R6: (a) /256 and /64 folded into MFMA MX scales (bit-exact),
// (b) dead H-stream skipped at the last hidden layer.
__global__ __launch_bounds__(512)
__attribute__((amdgpu_waves_per_eu(4, 4)))
void sympl_main(const float* __restrict__ X,
                const float* __restrict__ lW0, const float* __restrict__ lb0,
                const float* __restrict__ lbh, const float* __restrict__ lWo,
                const float* __restrict__ rW0, const float* __restrict__ rb0,
                const float* __restrict__ rbh, const float* __restrict__ rWo,
                const int* __restrict__ lidx, const int* __restrict__ ridx,
                const unsigned char* __restrict__ wbf,
                float* __restrict__ out)
{
  __shared__ __align__(16) unsigned char sWb[2*IMGB];   // weight double-buffer (flat)
  __shared__ __align__(16) unsigned char sH[2*16384];
  // parity P (0/16384): H row e at P + e*128, D at P + 8192 + e*128
  // element row e, 16B chunk c4: byte (c4 ^ (e&7))*16 within the row

  const int tid  = threadIdx.x;
  const int lane = tid & 63;
  const int w    = tid >> 6;        // wave 0..7
  const int m0   = lane & 15;
  const int q    = lane >> 4;
  const int g2   = w & 3;           // element group (16 elems each)
  const int ih   = w >> 2;          // n_out half (tiles ih*4 .. ih*4+3)
  const int col  = blockIdx.y;
  const int e0   = blockIdx.x * 64;
  const int r    = tid >> 3;        // element 0..63 (8 threads each)
  const int sg   = tid & 7;
  const int r7   = r & 7;
  const int m06  = m0 & 6;
  const int m07  = m0 & 7;

  const int lt = (lidx[0] == col) ? 0 : 1;
  const int rt = (ridx[0] == col) ? 0 : 1;

  float qv = X[(e0 + r)*4 + col];
  float pv = X[(e0 + r)*4 + 2 + col];

  const float dt = 0.1f;
  const float C0 = 0.6756035959798289f, C1 = -0.17560359597982883f;
  const float D0 = 1.3512071919596578f, D1 = -1.7024143839193153f;
  // fold 1/(16*4^7) = 1/262144 (final S_d scale) into the step coefficients
  const float is = 1.0f / 262144.0f;
  const float coefs[7] = { C0*dt*is, -D0*dt*is, C1*dt*is, -D1*dt*is,
                           C1*dt*is, -D0*dt*is, C0*dt*is };

  // hoisted, loop-invariant LDS addresses; parity (0/16384), stream (+8192) and
  // tile (i*2048) displacements fold into ds immediate offsets after full unroll.
  const int lo16 = (m0 & 1) * 16;
  const int opo  = ((2*q) ^ m06) * 16;
  const unsigned char* pB0lo = sH + (g2*16 + m0)*128 + opo + lo16;
  const unsigned char* pB0hi = sH + (g2*16 + m0)*128 + opo + 16 - lo16;
  const unsigned char* pA0lo = sWb + (ih*64 + m0)*128 + opo + lo16;
  const unsigned char* pA0hi = sWb + (ih*64 + m0)*128 + opo + 16 - lo16;
  unsigned char* pHe = sH + (g2*16 + m0)*128;                 // epilogue write base
  unsigned char* pL0 = sH + r*128 + ((sg ^ r7)*16);           // layer-0 write base (parity 0)
  const unsigned char* pRd = sH + 16384 + 8192 + r*128 + ((sg ^ r7)*16);  // reduce (parity 1, S_d)
  const int q4 = q * 4;
  unsigned char* pE0 = pHe + ((ih*4 + 0) ^ m07)*16 + q4;      // epilogue chunk pointers
  unsigned char* pE1 = pHe + ((ih*4 + 1) ^ m07)*16 + q4;
  unsigned char* pE2 = pHe + ((ih*4 + 2) ^ m07)*16 + q4;
  unsigned char* pE3 = pHe + ((ih*4 + 3) ^ m07)*16 + q4;

  // prologue: stage sW buffer 0 for ev=0 (right net, term rt, L=0)
  {
    const unsigned char* src = wbf + (size_t)(2 + rt)*NLAYER*IMGB;
    #pragma unroll
    for (int it = 0; it < 2; ++it){
      int o = (it*512 + tid) * 16;
      gl2lds16(src + o, sWb + o);
    }
  }
  __syncthreads();

  for (int ev = 0; ev < 7; ++ev){
    const bool isT = !(ev & 1);
    const int  evp = ev & 1;          // sW parity generator: par(L) = evp ^ (L&1)
    const int  term = isT ? rt : lt;
    const float* W0p = (isT ? rW0 : lW0) + term*128;
    const float* b0p = (isT ? rb0 : lb0) + term*128;
    const float* bhp = (isT ? rbh : lbh) + term*NLAYER*128;
    const float* Wop = (isT ? rWo : lWo) + term*128;
    const unsigned char* wimg = wbf + (size_t)(((isT ? 2 : 0) + term)*NLAYER)*IMGB;
    const int tnx = (ev & 1) ? rt : lt;
    const unsigned char* wimg_nx = wbf + (size_t)((((ev & 1) ? 2 : 0) + tnx)*NLAYER)*IMGB;

    // ---- layer 0: S_h = 16*gelu(z), S_d = 16*gelu'(z)*w, z = x*w+b  (parity 0) ----
    {
      const float x = isT ? pv : qv;
      const float2v xv = {x, x};
      unsigned hw[4], dw[4];
      #pragma unroll
      for (int c = 0; c < 2; ++c){
        int n0 = sg*16 + c*8;
        float4v wa = *(const float4v*)(W0p + n0);
        float4v wb = *(const float4v*)(W0p + n0 + 4);
        float4v ba = *(const float4v*)(b0p + n0);
        float4v bb2 = *(const float4v*)(b0p + n0 + 4);
        float2v zp[4] = { pk_fma(xv, lo2(wa), lo2(ba)), pk_fma(xv, hi2(wa), hi2(ba)),
                          pk_fma(xv, lo2(wb), lo2(bb2)), pk_fma(xv, hi2(wb), hi2(bb2)) };
        float2v wp[4] = { lo2(wa), hi2(wa), lo2(wb), hi2(wb) };
        float Sh[8], Sd[8];
        #pragma unroll
        for (int pp = 0; pp < 4; ++pp){
          float2v P16, gp16; act2(zp[pp], P16, gp16);
          float2v h = zp[pp] * P16;
          float2v d = gp16 * wp[pp];
          Sh[pp*2] = h[0]; Sh[pp*2+1] = h[1];
          Sd[pp*2] = d[0]; Sd[pp*2+1] = d[1];
        }
        hw[c*2]   = pk4fp8(Sh[0],Sh[1],Sh[2],Sh[3]);
        hw[c*2+1] = pk4fp8(Sh[4],Sh[5],Sh[6],Sh[7]);
        dw[c*2]   = pk4fp8(Sd[0],Sd[1],Sd[2],Sd[3]);
        dw[c*2+1] = pk4fp8(Sd[4],Sd[5],Sd[6],Sd[7]);
      }
      *(uint4v*)(pL0)        = (uint4v){hw[0], hw[1], hw[2], hw[3]};
      *(uint4v*)(pL0 + 8192) = (uint4v){dw[0], dw[1], dw[2], dw[3]};
    }
    asm volatile("s_waitcnt lgkmcnt(0)" ::: "memory");
    __builtin_amdgcn_s_barrier();
    asm volatile("" ::: "memory");

    // ---- hidden layers: ping-pong sH, ONE barrier per layer ----
    #pragma unroll
    for (int L = 0; L < NLAYER; ++L){
      const int rdo = (L & 1) * 16384;      // sH read parity (compile-time)
      const int wro = rdo ^ 16384;          // sH write parity
      const int par = (L & 1) ? (evp ^ 1) : evp;   // sW read buffer (uniform)
      const int bufo = par ? IMGB : 0;
      const bool last = (L == NLAYER-1);    // compile-time after unroll

      // bias loads FIRST (oldest vmem): epilogue's bias wait leaves staging in flight
      const float* bias = bhp + L*128 + ih*64 + q4;
      float4v bv0 = *(const float4v*)(bias);
      float4v bv1 = *(const float4v*)(bias + 16);
      float4v bv2 = *(const float4v*)(bias + 32);
      float4v bv3 = *(const float4v*)(bias + 48);

      // stage NEXT weight tile into the other sW buffer; drains at end-of-layer barrier
      if (!(ev == 6 && L == 6)){
        const unsigned char* nsrc = (L < 6) ? (wimg + (size_t)(L+1)*IMGB) : wimg_nx;
        unsigned char* dW = sWb + (bufo ^ IMGB);
        #pragma unroll
        for (int it = 0; it < 2; ++it){
          int o = (it*512 + tid) * 16;
          gl2lds16(nsrc + o, dW + o);
        }
      }

      const unsigned char* pAcLo = pA0lo + bufo;
      const unsigned char* pAcHi = pA0hi + bufo;
      int8v b0 = ld_op16(pB0lo + rdo, pB0hi + rdo);
      int8v b1 = ld_op16(pB0lo + rdo + 8192, pB0hi + rdo + 8192);
      float4v acc[4][2];
      #pragma unroll
      for (int i = 0; i < 4; ++i){
        int8v a = ld_op16(pAcLo + i*2048, pAcHi + i*2048);
        acc[i][0] = mfma128s(a, b0, 0x77777777u);   // product * 2^-8  (/256 folded)
        acc[i][1] = mfma128s(a, b1, 0x79797979u);   // product * 2^-6  (/64 folded)
      }

      // NO mid barrier: epilogue writes the OPPOSITE parity (no WAR with other waves' reads)
      // epilogue: z = acc0 + b (scale pre-folded); S_h' = z*P16; S_d' = gp16 * acc1
      // (last layer: H-stream is dead — skip its mul/pack/write)
      #define EPI(i, bvv, pe) { \
        float2v za = lo2(acc[i][0]) + lo2(bvv); \
        float2v zb = hi2(acc[i][0]) + hi2(bvv); \
        float2v ta = lo2(acc[i][1]); \
        float2v tb = hi2(acc[i][1]); \
        float2v Pa, ga, Pb, gb; \
        act2(za, Pa, ga); \
        act2(zb, Pb, gb); \
        float2v da = ga * ta, db = gb * tb; \
        if (!last){ \
          float2v ha = za * Pa, hb = zb * Pb; \
          *(unsigned*)(pe + wro) = pk4fp8(ha[0], ha[1], hb[0], hb[1]); \
        } \
        *(unsigned*)(pe + wro + 8192) = pk4fp8(da[0], da[1], db[0], db[1]); \
      }
      EPI(0, bv0, pE0)
      EPI(1, bv1, pE1)
      EPI(2, bv2, pE2)
      EPI(3, bv3, pE3)
      #undef EPI

      // ONE barrier per layer: orders this layer's sH writes (RAW for L+1) and
      // sH reads (WAR vs L+1 writes), and drains the sW staging DMA (vmcnt).
      asm volatile("s_waitcnt vmcnt(0) lgkmcnt(0)" ::: "memory");
      __builtin_amdgcn_s_barrier();
      asm volatile("" ::: "memory");
    }

    // ---- reduce: s_raw = S_d7 . Wo (= 262144*s); parity-1 D region. No trailing
    // barrier: next eval's conflicting writers sit behind the post-layer0 barrier. ----
    {
      uint4v dvv = *(const uint4v*)(pRd);
      float2v sv = {0.f, 0.f};
      float4v woa = *(const float4v*)(Wop + sg*16);
      float4v wob = *(const float4v*)(Wop + sg*16 + 4);
      float4v woc = *(const float4v*)(Wop + sg*16 + 8);
      float4v wod = *(const float4v*)(Wop + sg*16 + 12);
      sv = pk_fma(up2<false>(dvv[0]), lo2(woa), sv);
      sv = pk_fma(up2<true>(dvv[0]),  hi2(woa), sv);
      sv = pk_fma(up2<false>(dvv[1]), lo2(wob), sv);
      sv = pk_fma(up2<true>(dvv[1]),  hi2(wob), sv);
      sv = pk_fma(up2<false>(dvv[2]), lo2(woc), sv);
      sv = pk_fma(up2<true>(dvv[2]),  hi2(woc), sv);
      sv = pk_fma(up2<false>(dvv[3]), lo2(wod), sv);
      sv = pk_fma(up2<true>(dvv[3]),  hi2(wod), sv);
      float s = sv[0] + sv[1];
      s += __shfl_xor(s, 1);
      s += __shfl_xor(s, 2);
      s += __shfl_xor(s, 4);
      if (isT) qv += coefs[ev] * s;
      else     pv += coefs[ev] * s;
    }
  }

  if (sg == 0){
    out[(e0 + r)*4 + col]     = qv;
    out[(e0 + r)*4 + 2 + col] = pv;
  }
}

extern "C" void kernel_launch(void* const* d_in, const int* in_sizes, int n_in,
                              void* d_out, int out_size, void* d_ws, size_t ws_size,
                              hipStream_t stream)
{
  const float* X   = (const float*)d_in[0];
  const float* lW0 = (const float*)d_in[1];
  const float* lb0 = (const float*)d_in[2];
  const float* lWh = (const float*)d_in[3];
  const float* lbh = (const float*)d_in[4];
  const float* lWo = (const float*)d_in[5];
  const float* rW0 = (const float*)d_in[7];
  const float* rb0 = (const float*)d_in[8];
  const float* rWh = (const float*)d_in[9];
  const float* rbh = (const float*)d_in[10];
  const float* rWo = (const float*)d_in[11];
  const int*   li  = (const int*)d_in[13];
  const int*   ri  = (const int*)d_in[14];
  unsigned char* wbf = (unsigned char*)d_ws;   // 4*7*16384 B = 458752 B
  float* out = (float*)d_out;
  const int B = in_sizes[0] / 4;

  hipLaunchKernelGGL(prep_weights, dim3(4*NLAYER), dim3(256), 0, stream,
                     lWh, rWh, wbf);
  hipLaunchKernelGGL(sympl_main, dim3(B/64, 2), dim3(512), 0, stream,
                     X, lW0, lb0, lbh, lWo, rW0, rb0, rbh, rWo, li, ri, wbf, out);
}

// Round 13
// 180.214 us; speedup vs baseline: 1.0630x; 1.0060x over previous
//
#include <hip/hip_runtime.h>

#define NLAYER 7
#define IMGB 16384          // bytes per weight-layer image: A[n][k] fp8, 16B-chunk XOR-swizzled (key n&7)
#define WSCALE 16.0f        // weights stored x16 (e4m3 subnormal protection)

typedef __attribute__((ext_vector_type(2))) float float2v;
typedef __attribute__((ext_vector_type(4))) float float4v;
typedef __attribute__((ext_vector_type(4))) unsigned int uint4v;
typedef __attribute__((ext_vector_type(4))) int int4v;
typedef __attribute__((ext_vector_type(8))) int int8v;
typedef unsigned long long u64;

__device__ __forceinline__ float2v pk_fma(float2v a, float2v b, float2v c){
  return __builtin_elementwise_fma(a, b, c);
}
__device__ __forceinline__ float2v lo2(float4v v){ return (float2v){v[0], v[1]}; }
__device__ __forceinline__ float2v hi2(float4v v){ return (float2v){v[2], v[3]}; }

// pack 4 f32 -> 4 fp8 e4m3 bytes (ascending)
__device__ __forceinline__ unsigned pk4fp8(float v0, float v1, float v2, float v3){
  int w = __builtin_amdgcn_cvt_pk_fp8_f32(v0, v1, 0, false);
  w = __builtin_amdgcn_cvt_pk_fp8_f32(v2, v3, w, true);
  return (unsigned)w;
}
template<bool HI>
__device__ __forceinline__ float2v up2(unsigned w){
  return __builtin_amdgcn_cvt_pk_f32_fp8((int)w, HI);
}
// MX-scaled MFMA, K=128, FMT=fp8 e4m3 both operands. `sc` is the E8M0 scale
// for the first scale slot (4 packed bytes, one per 32-elem K-block): 0x7F=2^0.
// Scaling either operand scales the product -> folding /256 (0x77) and /64
// (0x79) here is bit-identical to the old epilogue divides (powers of two).
__device__ __forceinline__ float4v mfma128s(int8v a, int8v b, unsigned sc){
  return __builtin_amdgcn_mfma_scale_f32_16x16x128_f8f6f4(
      a, b, (float4v){0.f,0.f,0.f,0.f}, 0, 0, 0, (int)sc, 0, 0x7F7F7F7F);
}
// P16 = 16*Phi(z) (cubic Taylor), gp16 = 16*gelu'(z)
__device__ __forceinline__ void act2(float2v z, float2v& P16, float2v& gp16){
  const float2v c1v  = {6.3830764862829235f, 6.3830764862829235f};
  const float2v c3v  = {-1.0638460810704874f, -1.0638460810704874f};
  const float2v c33v = {-3.1915382432114624f, -3.1915382432114624f};
  const float2v v8   = {8.f, 8.f};
  float2v z2 = z * z;
  float2v u  = pk_fma(z2, c3v, c1v);
  P16 = pk_fma(z, u, v8);
  float2v Pd = pk_fma(z2, c33v, c1v);
  gp16 = pk_fma(z, Pd, P16);
}

__device__ __forceinline__ void gl2lds16(const unsigned char* g, unsigned char* l){
  __builtin_amdgcn_global_load_lds((const __attribute__((address_space(1))) unsigned int*)g,
                                   (__attribute__((address_space(3))) unsigned int*)l,
                                   16, 0, 0);
}

// operand gather: 32 contiguous k-bytes from a 16B-swizzled row (key row&7).
// lp/hp pre-compensate the key-bit0 half-swap so k-order is preserved; all
// per-layer/tile displacements fold into ds_read immediate offsets.
__device__ __forceinline__ int8v ld_op16(const unsigned char* lp, const unsigned char* hp){
  int4v lo = *(const int4v*)(lp);
  int4v hi = *(const int4v*)(hp);
  return __builtin_shufflevector(lo, hi, 0, 1, 2, 3, 4, 5, 6, 7);
}

// ---- prep: Wh fp32 [side][term][L][k][n] -> fp8 image [net][L][n][16B chunk c4 ^ (n&7)], W*16 ----
__global__ __launch_bounds__(256)
void prep_weights(const float* __restrict__ lWh,
                  const float* __restrict__ rWh,
                  unsigned char* __restrict__ wbf)
{
  __shared__ __align__(16) unsigned char T[IMGB];
  const int b = blockIdx.x;               // net*7 + L
  const int net = b / NLAYER, L = b % NLAYER;
  const int side = net >> 1, term = net & 1;
  const float* src = (side ? rWh : lWh) + (size_t)((term*NLAYER + L)*128)*128;
  const int t = threadIdx.x;
  {
    const int k = t >> 1, n0 = (t & 1)*64;
    const float* row = src + k*128 + n0;
    #pragma unroll
    for (int c4 = 0; c4 < 4; ++c4){
      float4v f0 = *(const float4v*)(row + c4*16);
      float4v f1 = *(const float4v*)(row + c4*16 + 4);
      float4v f2 = *(const float4v*)(row + c4*16 + 8);
      float4v f3 = *(const float4v*)(row + c4*16 + 12);
      uint4v wv = { pk4fp8(f0[0]*WSCALE, f0[1]*WSCALE, f0[2]*WSCALE, f0[3]*WSCALE),
                    pk4fp8(f1[0]*WSCALE, f1[1]*WSCALE, f1[2]*WSCALE, f1[3]*WSCALE),
                    pk4fp8(f2[0]*WSCALE, f2[1]*WSCALE, f2[2]*WSCALE, f2[3]*WSCALE),
                    pk4fp8(f3[0]*WSCALE, f3[1]*WSCALE, f3[2]*WSCALE, f3[3]*WSCALE) };
      *(uint4v*)&T[k*128 + n0 + c4*16] = wv;
    }
  }
  __syncthreads();
  {
    const int n = t >> 1, c0 = (t & 1)*8;
    const int sw7 = n & 7;
    unsigned char* dst = wbf + ((size_t)b << 14) + n*128;
    #pragma unroll
    for (int c = 0; c < 8; ++c){
      const int c64 = c0 + c;                 // u64 chunk 0..15, k in [c64*8, c64*8+8)
      const int kc = c64*8;
      u64 v = 0;
      #pragma unroll
      for (int j = 0; j < 8; ++j)
        v |= (u64)T[(kc + j)*128 + n] << (8*j);
      *(u64*)(dst + (((c64 >> 1) ^ sw7)*16) + (c64 & 1)*8) = v;
    }
  }
}

// R12 champion structure: 512 thr / 8 waves / 64 elems; sH ping-pong (2x16KB) ->
// ONE barrier per layer; sW double-buffered (flat) with full-layer staging
// overlap; /256 and /64 folded into MFMA MX scales; dead H-stream skipped at
// the last hidden layer. LDS = 64KB -> exactly 2 blocks/CU.
// Deltas vs R12: (a) s_setprio(1) around the ds_read+MFMA critical section
// (T5 — pays only via cross-BLOCK wave role diversity; 2 indep blocks/CU),
// (b) Wo loads hoisted to eval start (off the post-L6-barrier serial path).
__global__ __launch_bounds__(512)
__attribute__((amdgpu_waves_per_eu(4, 4)))
void sympl_main(const float* __restrict__ X,
                const float* __restrict__ lW0, const float* __restrict__ lb0,
                const float* __restrict__ lbh, const float* __restrict__ lWo,
                const float* __restrict__ rW0, const float* __restrict__ rb0,
                const float* __restrict__ rbh, const float* __restrict__ rWo,
                const int* __restrict__ lidx, const int* __restrict__ ridx,
                const unsigned char* __restrict__ wbf,
                float* __restrict__ out)
{
  __shared__ __align__(16) unsigned char sWb[2*IMGB];   // weight double-buffer (flat)
  __shared__ __align__(16) unsigned char sH[2*16384];
  // parity P (0/16384): H row e at P + e*128, D at P + 8192 + e*128
  // element row e, 16B chunk c4: byte (c4 ^ (e&7))*16 within the row

  const int tid  = threadIdx.x;
  const int lane = tid & 63;
  const int w    = tid >> 6;        // wave 0..7
  const int m0   = lane & 15;
  const int q    = lane >> 4;
  const int g2   = w & 3;           // element group (16 elems each)
  const int ih   = w >> 2;          // n_out half (tiles ih*4 .. ih*4+3)
  const int col  = blockIdx.y;
  const int e0   = blockIdx.x * 64;
  const int r    = tid >> 3;        // element 0..63 (8 threads each)
  const int sg   = tid & 7;
  const int r7   = r & 7;
  const int m06  = m0 & 6;
  const int m07  = m0 & 7;

  const int lt = (lidx[0] == col) ? 0 : 1;
  const int rt = (ridx[0] == col) ? 0 : 1;

  float qv = X[(e0 + r)*4 + col];
  float pv = X[(e0 + r)*4 + 2 + col];

  const float dt = 0.1f;
  const float C0 = 0.6756035959798289f, C1 = -0.17560359597982883f;
  const float D0 = 1.3512071919596578f, D1 = -1.7024143839193153f;
  // fold 1/(16*4^7) = 1/262144 (final S_d scale) into the step coefficients
  const float is = 1.0f / 262144.0f;
  const float coefs[7] = { C0*dt*is, -D0*dt*is, C1*dt*is, -D1*dt*is,
                           C1*dt*is, -D0*dt*is, C0*dt*is };

  // hoisted, loop-invariant LDS addresses; parity (0/16384), stream (+8192) and
  // tile (i*2048) displacements fold into ds immediate offsets after full unroll.
  const int lo16 = (m0 & 1) * 16;
  const int opo  = ((2*q) ^ m06) * 16;
  const unsigned char* pB0lo = sH + (g2*16 + m0)*128 + opo + lo16;
  const unsigned char* pB0hi = sH + (g2*16 + m0)*128 + opo + 16 - lo16;
  const unsigned char* pA0lo = sWb + (ih*64 + m0)*128 + opo + lo16;
  const unsigned char* pA0hi = sWb + (ih*64 + m0)*128 + opo + 16 - lo16;
  unsigned char* pHe = sH + (g2*16 + m0)*128;                 // epilogue write base
  unsigned char* pL0 = sH + r*128 + ((sg ^ r7)*16);           // layer-0 write base (parity 0)
  const unsigned char* pRd = sH + 16384 + 8192 + r*128 + ((sg ^ r7)*16);  // reduce (parity 1, S_d)
  const int q4 = q * 4;
  unsigned char* pE0 = pHe + ((ih*4 + 0) ^ m07)*16 + q4;      // epilogue chunk pointers
  unsigned char* pE1 = pHe + ((ih*4 + 1) ^ m07)*16 + q4;
  unsigned char* pE2 = pHe + ((ih*4 + 2) ^ m07)*16 + q4;
  unsigned char* pE3 = pHe + ((ih*4 + 3) ^ m07)*16 + q4;

  // prologue: stage sW buffer 0 for ev=0 (right net, term rt, L=0)
  {
    const unsigned char* src = wbf + (size_t)(2 + rt)*NLAYER*IMGB;
    #pragma unroll
    for (int it = 0; it < 2; ++it){
      int o = (it*512 + tid) * 16;
      gl2lds16(src + o, sWb + o);
    }
  }
  __syncthreads();

  for (int ev = 0; ev < 7; ++ev){
    const bool isT = !(ev & 1);
    const int  evp = ev & 1;          // sW parity generator: par(L) = evp ^ (L&1)
    const int  term = isT ? rt : lt;
    const float* W0p = (isT ? rW0 : lW0) + term*128;
    const float* b0p = (isT ? rb0 : lb0) + term*128;
    const float* bhp = (isT ? rbh : lbh) + term*NLAYER*128;
    const float* Wop = (isT ? rWo : lWo) + term*128;
    const unsigned char* wimg = wbf + (size_t)(((isT ? 2 : 0) + term)*NLAYER)*IMGB;
    const int tnx = (ev & 1) ? rt : lt;
    const unsigned char* wimg_nx = wbf + (size_t)((((ev & 1) ? 2 : 0) + tnx)*NLAYER)*IMGB;

    // Wo loads hoisted to eval start: eval-invariant, consumed in the reduce.
    // Issued here so their L2 latency hides under the whole eval instead of
    // sitting on the post-L6-barrier serial path.
    float4v woa = *(const float4v*)(Wop + sg*16);
    float4v wob = *(const float4v*)(Wop + sg*16 + 4);
    float4v woc = *(const float4v*)(Wop + sg*16 + 8);
    float4v wod = *(const float4v*)(Wop + sg*16 + 12);

    // ---- layer 0: S_h = 16*gelu(z), S_d = 16*gelu'(z)*w, z = x*w+b  (parity 0) ----
    {
      const float x = isT ? pv : qv;
      const float2v xv = {x, x};
      unsigned hw[4], dw[4];
      #pragma unroll
      for (int c = 0; c < 2; ++c){
        int n0 = sg*16 + c*8;
        float4v wa = *(const float4v*)(W0p + n0);
        float4v wb = *(const float4v*)(W0p + n0 + 4);
        float4v ba = *(const float4v*)(b0p + n0);
        float4v bb2 = *(const float4v*)(b0p + n0 + 4);
        float2v zp[4] = { pk_fma(xv, lo2(wa), lo2(ba)), pk_fma(xv, hi2(wa), hi2(ba)),
                          pk_fma(xv, lo2(wb), lo2(bb2)), pk_fma(xv, hi2(wb), hi2(bb2)) };
        float2v wp[4] = { lo2(wa), hi2(wa), lo2(wb), hi2(wb) };
        float Sh[8], Sd[8];
        #pragma unroll
        for (int pp = 0; pp < 4; ++pp){
          float2v P16, gp16; act2(zp[pp], P16, gp16);
          float2v h = zp[pp] * P16;
          float2v d = gp16 * wp[pp];
          Sh[pp*2] = h[0]; Sh[pp*2+1] = h[1];
          Sd[pp*2] = d[0]; Sd[pp*2+1] = d[1];
        }
        hw[c*2]   = pk4fp8(Sh[0],Sh[1],Sh[2],Sh[3]);
        hw[c*2+1] = pk4fp8(Sh[4],Sh[5],Sh[6],Sh[7]);
        dw[c*2]   = pk4fp8(Sd[0],Sd[1],Sd[2],Sd[3]);
        dw[c*2+1] = pk4fp8(Sd[4],Sd[5],Sd[6],Sd[7]);
      }
      *(uint4v*)(pL0)        = (uint4v){hw[0], hw[1], hw[2], hw[3]};
      *(uint4v*)(pL0 + 8192) = (uint4v){dw[0], dw[1], dw[2], dw[3]};
    }
    asm volatile("s_waitcnt lgkmcnt(0)" ::: "memory");
    __builtin_amdgcn_s_barrier();
    asm volatile("" ::: "memory");

    // ---- hidden layers: ping-pong sH, ONE barrier per layer ----
    #pragma unroll
    for (int L = 0; L < NLAYER; ++L){
      const int rdo = (L & 1) * 16384;      // sH read parity (compile-time)
      const int wro = rdo ^ 16384;          // sH write parity
      const int par = (L & 1) ? (evp ^ 1) : evp;   // sW read buffer (uniform)
      const int bufo = par ? IMGB : 0;
      const bool last = (L == NLAYER-1);    // compile-time after unroll

      // bias loads FIRST (oldest vmem): epilogue's bias wait leaves staging in flight
      const float* bias = bhp + L*128 + ih*64 + q4;
      float4v bv0 = *(const float4v*)(bias);
      float4v bv1 = *(const float4v*)(bias + 16);
      float4v bv2 = *(const float4v*)(bias + 32);
      float4v bv3 = *(const float4v*)(bias + 48);

      // stage NEXT weight tile into the other sW buffer; drains at end-of-layer barrier
      if (!(ev == 6 && L == 6)){
        const unsigned char* nsrc = (L < 6) ? (wimg + (size_t)(L+1)*IMGB) : wimg_nx;
        unsigned char* dW = sWb + (bufo ^ IMGB);
        #pragma unroll
        for (int it = 0; it < 2; ++it){
          int o = (it*512 + tid) * 16;
          gl2lds16(nsrc + o, dW + o);
        }
      }

      // critical section: LDS operand reads + MFMA. Priority-boosted (T5):
      // with 2 independent blocks/CU the other block's waves are typically in
      // staging/epilogue -> arbitration favors the matrix-feeding waves.
      __builtin_amdgcn_s_setprio(1);
      const unsigned char* pAcLo = pA0lo + bufo;
      const unsigned char* pAcHi = pA0hi + bufo;
      int8v b0 = ld_op16(pB0lo + rdo, pB0hi + rdo);
      int8v b1 = ld_op16(pB0lo + rdo + 8192, pB0hi + rdo + 8192);
      float4v acc[4][2];
      #pragma unroll
      for (int i = 0; i < 4; ++i){
        int8v a = ld_op16(pAcLo + i*2048, pAcHi + i*2048);
        acc[i][0] = mfma128s(a, b0, 0x77777777u);   // product * 2^-8  (/256 folded)
        acc[i][1] = mfma128s(a, b1, 0x79797979u);   // product * 2^-6  (/64 folded)
      }
      __builtin_amdgcn_s_setprio(0);

      // NO mid barrier: epilogue writes the OPPOSITE parity (no WAR with other waves' reads)
      // epilogue: z = acc0 + b (scale pre-folded); S_h' = z*P16; S_d' = gp16 * acc1
      // (last layer: H-stream is dead — skip its mul/pack/write)
      #define EPI(i, bvv, pe) { \
        float2v za = lo2(acc[i][0]) + lo2(bvv); \
        float2v zb = hi2(acc[i][0]) + hi2(bvv); \
        float2v ta = lo2(acc[i][1]); \
        float2v tb = hi2(acc[i][1]); \
        float2v Pa, ga, Pb, gb; \
        act2(za, Pa, ga); \
        act2(zb, Pb, gb); \
        float2v da = ga * ta, db = gb * tb; \
        if (!last){ \
          float2v ha = za * Pa, hb = zb * Pb; \
          *(unsigned*)(pe + wro) = pk4fp8(ha[0], ha[1], hb[0], hb[1]); \
        } \
        *(unsigned*)(pe + wro + 8192) = pk4fp8(da[0], da[1], db[0], db[1]); \
      }
      EPI(0, bv0, pE0)
      EPI(1, bv1, pE1)
      EPI(2, bv2, pE2)
      EPI(3, bv3, pE3)
      #undef EPI

      // ONE barrier per layer: orders this layer's sH writes (RAW for L+1) and
      // sH reads (WAR vs L+1 writes), and drains the sW staging DMA (vmcnt).
      asm volatile("s_waitcnt vmcnt(0) lgkmcnt(0)" ::: "memory");
      __builtin_amdgcn_s_barrier();
      asm volatile("" ::: "memory");
    }

    // ---- reduce: s_raw = S_d7 . Wo (= 262144*s); parity-1 D region. No trailing
    // barrier: next eval's conflicting writers sit behind the post-layer0 barrier. ----
    {
      uint4v dvv = *(const uint4v*)(pRd);
      float2v sv = {0.f, 0.f};
      sv = pk_fma(up2<false>(dvv[0]), lo2(woa), sv);
      sv = pk_fma(up2<true>(dvv[0]),  hi2(woa), sv);
      sv = pk_fma(up2<false>(dvv[1]), lo2(wob), sv);
      sv = pk_fma(up2<true>(dvv[1]),  hi2(wob), sv);
      sv = pk_fma(up2<false>(dvv[2]), lo2(woc), sv);
      sv = pk_fma(up2<true>(dvv[2]),  hi2(woc), sv);
      sv = pk_fma(up2<false>(dvv[3]), lo2(wod), sv);
      sv = pk_fma(up2<true>(dvv[3]),  hi2(wod), sv);
      float s = sv[0] + sv[1];
      s += __shfl_xor(s, 1);
      s += __shfl_xor(s, 2);
      s += __shfl_xor(s, 4);
      if (isT) qv += coefs[ev] * s;
      else     pv += coefs[ev] * s;
    }
  }

  if (sg == 0){
    out[(e0 + r)*4 + col]     = qv;
    out[(e0 + r)*4 + 2 + col] = pv;
  }
}

extern "C" void kernel_launch(void* const* d_in, const int* in_sizes, int n_in,
                              void* d_out, int out_size, void* d_ws, size_t ws_size,
                              hipStream_t stream)
{
  const float* X   = (const float*)d_in[0];
  const float* lW0 = (const float*)d_in[1];
  const float* lb0 = (const float*)d_in[2];
  const float* lWh = (const float*)d_in[3];
  const float* lbh = (const float*)d_in[4];
  const float* lWo = (const float*)d_in[5];
  const float* rW0 = (const float*)d_in[7];
  const float* rb0 = (const float*)d_in[8];
  const float* rWh = (const float*)d_in[9];
  const float* rbh = (const float*)d_in[10];
  const float* rWo = (const float*)d_in[11];
  const int*   li  = (const int*)d_in[13];
  const int*   ri  = (const int*)d_in[14];
  unsigned char* wbf = (unsigned char*)d_ws;   // 4*7*16384 B = 458752 B
  float* out = (float*)d_out;
  const int B = in_sizes[0] / 4;

  hipLaunchKernelGGL(prep_weights, dim3(4*NLAYER), dim3(256), 0, stream,
                     lWh, rWh, wbf);
  hipLaunchKernelGGL(sympl_main, dim3(B/64, 2), dim3(512), 0, stream,
                     X, lW0, lb0, lbh, lWo, rW0, rb0, rbh, rWo, li, ri, wbf, out);
}